// Round 2
// baseline (230.632 us; speedup 1.0000x reference)
//
#include <hip/hip_runtime.h>
#include <math.h>

namespace {
constexpr int Bc = 2, Nc = 5, Cc = 64, Ac = 2, Hc = 128, Wc = 256;
constexpr int SUMN = Bc * Nc;
constexpr int HW = Hc * Wc;
constexpr float THRESH = 0.01f;
constexpr int CPT = 4;  // channels per thread in k_feat

// d_ws layout:
//   float [0..60)   : theta, 10 agents x 6
//   int   [64..74)  : owner flags
//   int   [80..90)  : cnt (final & vis)
//   int   [96..106) : cnt vis
//   byte  [512 .. 512 + B*HW) : per-pixel 5-bit agent mask
constexpr int OWNER_OFF = 64, NUM_OFF = 80, VIS_OFF = 96, MASK_BYTE_OFF = 512;

__global__ void k_setup(const float* __restrict__ nam, float* __restrict__ wsf,
                        int* __restrict__ wsi) {
  int tid = threadIdx.x;
  if (tid < SUMN) {
    int b = tid / Nc, j = tid % Nc;
    const float* src = nam + (size_t)(b * Nc * Nc + j) * 6;  // nam[b,0,j,:,:]
#pragma unroll
    for (int k = 0; k < 6; ++k) wsf[tid * 6 + k] = src[k];
    wsi[NUM_OFF + tid] = 0;
    wsi[VIS_OFF + tid] = 0;
    wsi[OWNER_OFF + tid] = (j == 0) ? 1 : 0;
  }
  __syncthreads();
  if (tid < Bc) {
    int b = tid;
    float d2[Nc];
    for (int j = 0; j < Nc; ++j) {
      float tx = nam[(size_t)(b * Nc * Nc + j) * 6 + 2];
      float ty = nam[(size_t)(b * Nc * Nc + j) * 6 + 5];
      d2[j] = tx * tx + ty * ty;
    }
    d2[0] = INFINITY;  // ego excluded from top-k
    int i1 = -1; float b1 = INFINITY;
    for (int j = 0; j < Nc; ++j) if (d2[j] < b1) { b1 = d2[j]; i1 = j; }
    int i2 = -1; float b2 = INFINITY;
    for (int j = 0; j < Nc; ++j) if (j != i1 && d2[j] < b2) { b2 = d2[j]; i2 = j; }
    if (i1 >= 0) wsi[OWNER_OFF + b * Nc + i1] = 1;
    if (i2 >= 0) wsi[OWNER_OFF + b * Nc + i2] = 1;
  }
}

// One thread per (b,h,w) pixel: vis + comm + final for all 5 agents,
// packs final bits into a byte mask, accumulates exact integer counters.
__global__ void __launch_bounds__(256) k_mask(const float* __restrict__ psm,
                                              const float* __restrict__ wsf,
                                              int* __restrict__ wsi,
                                              unsigned char* __restrict__ mask) {
  int t = blockIdx.x * blockDim.x + threadIdx.x;  // [0, B*HW)
  int b = t >> 15;
  int h = (t >> 8) & (Hc - 1);
  int w = t & (Wc - 1);
  float gx = -1.0f + (float)w * (2.0f / (Wc - 1));
  float gy = -1.0f + (float)h * (2.0f / (Hc - 1));
  unsigned m = 0;
#pragma unroll
  for (int j = 0; j < Nc; ++j) {
    int l = b * Nc + j;
    float t00 = wsf[l * 6 + 0], t01 = wsf[l * 6 + 1], t02 = wsf[l * 6 + 2];
    float t10 = wsf[l * 6 + 3], t11 = wsf[l * 6 + 4], t12 = wsf[l * 6 + 5];
    float cx = t00 * gx + t01 * gy + t02;
    float cy = t10 * gx + t11 * gy + t12;
    float ix = (cx + 1.0f) * 0.5f * (float)(Wc - 1);
    float iy = (cy + 1.0f) * 0.5f * (float)(Hc - 1);
    // vis: nearest sample of ones => in-bounds test of rounded coords
    int rx = (int)rintf(ix), ry = (int)rintf(iy);
    int vis = (rx >= 0 && rx < Wc && ry >= 0 && ry < Hc) ? 1 : 0;
    int comm = 1;  // agent 0 forced to 1
    if (j != 0) {
      float x0f = floorf(ix), y0f = floorf(iy);
      float fx = ix - x0f, fy = iy - y0f;
      int x0 = (int)x0f, y0 = (int)y0f;
      int x1 = x0 + 1, y1 = y0 + 1;
      bool vx0 = (x0 >= 0) && (x0 < Wc), vx1 = (x1 >= 0) && (x1 < Wc);
      bool vy0 = (y0 >= 0) && (y0 < Hc), vy1 = (y1 >= 0) && (y1 < Hc);
      float smax = -1.0f;
#pragma unroll
      for (int a = 0; a < Ac; ++a) {
        const float* p = psm + (size_t)(l * Ac + a) * HW;
        float v00 = (vy0 && vx0) ? p[y0 * Wc + x0] : 0.0f;
        float v01 = (vy0 && vx1) ? p[y0 * Wc + x1] : 0.0f;
        float v10 = (vy1 && vx0) ? p[y1 * Wc + x0] : 0.0f;
        float v11 = (vy1 && vx1) ? p[y1 * Wc + x1] : 0.0f;
        float v = v00 * (1.0f - fy) * (1.0f - fx) + v01 * (1.0f - fy) * fx +
                  v10 * fy * (1.0f - fx) + v11 * fy * fx;
        float s = 1.0f / (1.0f + expf(-v));
        smax = fmaxf(smax, s);
      }
      comm = (smax > THRESH) ? 1 : 0;
    }
    int owner = wsi[OWNER_OFF + l];
    int fin = comm & owner;
    m |= (unsigned)fin << j;
    // exact integer counts: one atomic per wave per agent
    unsigned long long bv = __ballot(vis != 0);
    unsigned long long bf = __ballot((fin & vis) != 0);
    if ((threadIdx.x & 63) == 0) {
      atomicAdd(&wsi[VIS_OFF + l], (int)__popcll(bv));
      atomicAdd(&wsi[NUM_OFF + l], (int)__popcll(bf));
    }
  }
  mask[t] = (unsigned char)m;
}

// One thread per (b, c-quad, h, w): 4 channels share coords/weights/mask.
// out[b,c,h,w] = max_j final_j * bilinear(x[b*5+j, c]).
__global__ void __launch_bounds__(256) k_feat(const float* __restrict__ x,
                                              const float* __restrict__ wsf,
                                              const unsigned char* __restrict__ mask,
                                              float* __restrict__ out) {
  int t = blockIdx.x * blockDim.x + threadIdx.x;  // [0, B*(C/4)*HW)
  int w = t & (Wc - 1);
  int h = (t >> 8) & (Hc - 1);
  int c4 = (t >> 15) & (Cc / CPT - 1);
  int b = t >> 19;
  int pix = (b << 15) | (h << 8) | w;
  unsigned m = mask[pix];
  float gx = -1.0f + (float)w * (2.0f / (Wc - 1));
  float gy = -1.0f + (float)h * (2.0f / (Hc - 1));
  float best[CPT];
#pragma unroll
  for (int k = 0; k < CPT; ++k) best[k] = 0.0f;
#pragma unroll
  for (int j = 0; j < Nc; ++j) {
    if (m & (1u << j)) {
      int l = b * Nc + j;
      float t00 = wsf[l * 6 + 0], t01 = wsf[l * 6 + 1], t02 = wsf[l * 6 + 2];
      float t10 = wsf[l * 6 + 3], t11 = wsf[l * 6 + 4], t12 = wsf[l * 6 + 5];
      float cx = t00 * gx + t01 * gy + t02;
      float cy = t10 * gx + t11 * gy + t12;
      float ix = (cx + 1.0f) * 0.5f * (float)(Wc - 1);
      float iy = (cy + 1.0f) * 0.5f * (float)(Hc - 1);
      float x0f = floorf(ix), y0f = floorf(iy);
      float fx = ix - x0f, fy = iy - y0f;
      int x0 = (int)x0f, y0 = (int)y0f;
      int x1 = x0 + 1, y1 = y0 + 1;
      bool vx0 = (x0 >= 0) && (x0 < Wc), vx1 = (x1 >= 0) && (x1 < Wc);
      bool vy0 = (y0 >= 0) && (y0 < Hc), vy1 = (y1 >= 0) && (y1 < Hc);
      bool v00 = vy0 && vx0, v01 = vy0 && vx1, v10 = vy1 && vx0, v11 = vy1 && vx1;
      int o00 = y0 * Wc + x0, o01 = y0 * Wc + x1;
      int o10 = y1 * Wc + x0, o11 = y1 * Wc + x1;
      float w00 = (1.0f - fy) * (1.0f - fx), w01 = (1.0f - fy) * fx;
      float w10 = fy * (1.0f - fx), w11 = fy * fx;
      const float* p = x + ((size_t)(l * Cc + c4 * CPT)) * HW;
#pragma unroll
      for (int k = 0; k < CPT; ++k) {
        float a00 = v00 ? p[o00] : 0.0f;
        float a01 = v01 ? p[o01] : 0.0f;
        float a10 = v10 ? p[o10] : 0.0f;
        float a11 = v11 ? p[o11] : 0.0f;
        float val = a00 * w00 + a01 * w01 + a10 * w10 + a11 * w11;
        best[k] = fmaxf(best[k], val);
        p += HW;
      }
    }
  }
  size_t obase = ((size_t)(b * Cc + c4 * CPT)) * HW + (h << 8) + w;
#pragma unroll
  for (int k = 0; k < CPT; ++k) {
    __builtin_nontemporal_store(best[k], &out[obase + (size_t)k * HW]);
  }
}

__global__ void k_rate(const int* __restrict__ wsi, float* __restrict__ out) {
  float s = 0.0f;
  for (int l = 0; l < SUMN; ++l) {
    float num = (float)wsi[NUM_OFF + l];
    float den = fmaxf((float)wsi[VIS_OFF + l], 1.0f);
    s += num / den;
  }
  out[(size_t)Bc * Cc * HW] = s / (float)SUMN;
}

}  // namespace

extern "C" void kernel_launch(void* const* d_in, const int* in_sizes, int n_in,
                              void* d_out, int out_size, void* d_ws, size_t ws_size,
                              hipStream_t stream) {
  const float* x = (const float*)d_in[0];
  const float* psm = (const float*)d_in[1];
  const float* nam = (const float*)d_in[2];
  // d_in[3] = record_len (compile-time constant Nc)
  float* out = (float*)d_out;
  float* wsf = (float*)d_ws;
  int* wsi = (int*)d_ws;
  unsigned char* mask = (unsigned char*)d_ws + MASK_BYTE_OFF;

  hipLaunchKernelGGL(k_setup, dim3(1), dim3(64), 0, stream, nam, wsf, wsi);
  hipLaunchKernelGGL(k_mask, dim3((Bc * HW) / 256), dim3(256), 0, stream, psm, wsf, wsi, mask);
  hipLaunchKernelGGL(k_feat, dim3((Bc * (Cc / CPT) * HW) / 256), dim3(256), 0, stream, x, wsf,
                     mask, out);
  hipLaunchKernelGGL(k_rate, dim3(1), dim3(1), 0, stream, wsi, out);
}

// Round 4
// 138.737 us; speedup vs baseline: 1.6624x; 1.6624x over previous
//
#include <hip/hip_runtime.h>
#include <math.h>

namespace {
constexpr int Bc = 2, Nc = 5, Cc = 64, Ac = 2, Hc = 128, Wc = 256;
constexpr int SUMN = Bc * Nc;
constexpr int HW = Hc * Wc;
// sigmoid(v) > 0.01  <=>  v > log(0.01/0.99)
constexpr float LOGIT_THRESH = -4.59511985013459f;
constexpr int CPT = 8;  // channels per thread in k_feat
constexpr int MASK_BLOCKS = (Bc * HW) / 256;  // 256 blocks in k_mask

// d_ws layout (int offsets):
//   float [0..60)      : theta, 10 agents x 6
//   int   [64..74)     : owner flags
//   int   [128..2688)  : per-block partial counts, [blk][j*2 + {vis,num}]
//   byte  11264 ..     : per-pixel 5-bit agent mask (B*HW bytes)
constexpr int OWNER_OFF = 64, PART_OFF = 128;
constexpr int MASK_BYTE_OFF = 11264;

__global__ void k_setup(const float* __restrict__ nam, float* __restrict__ wsf,
                        int* __restrict__ wsi) {
  int tid = threadIdx.x;
  if (tid < SUMN) {
    int b = tid / Nc, j = tid % Nc;
    const float* src = nam + (size_t)(b * Nc * Nc + j) * 6;  // nam[b,0,j,:,:]
#pragma unroll
    for (int k = 0; k < 6; ++k) wsf[tid * 6 + k] = src[k];
    wsi[OWNER_OFF + tid] = (j == 0) ? 1 : 0;
  }
  __syncthreads();
  if (tid < Bc) {
    int b = tid;
    float d2[Nc];
    for (int j = 0; j < Nc; ++j) {
      float tx = nam[(size_t)(b * Nc * Nc + j) * 6 + 2];
      float ty = nam[(size_t)(b * Nc * Nc + j) * 6 + 5];
      d2[j] = tx * tx + ty * ty;
    }
    d2[0] = INFINITY;  // ego excluded from top-k
    int i1 = -1; float b1 = INFINITY;
    for (int j = 0; j < Nc; ++j) if (d2[j] < b1) { b1 = d2[j]; i1 = j; }
    int i2 = -1; float b2 = INFINITY;
    for (int j = 0; j < Nc; ++j) if (j != i1 && d2[j] < b2) { b2 = d2[j]; i2 = j; }
    if (i1 >= 0) wsi[OWNER_OFF + b * Nc + i1] = 1;
    if (i2 >= 0) wsi[OWNER_OFF + b * Nc + i2] = 1;
  }
}

// One thread per (b,h,w) pixel. No global atomics: ballots -> LDS -> one
// non-atomic partial-count record per block.
__global__ void __launch_bounds__(256) k_mask(const float* __restrict__ psm,
                                              const float* __restrict__ wsf,
                                              const int* __restrict__ wsi,
                                              int* __restrict__ partial,
                                              unsigned char* __restrict__ mask) {
  __shared__ int cnt[Nc * 2];
  int tid = threadIdx.x;
  if (tid < Nc * 2) cnt[tid] = 0;
  __syncthreads();

  int t = blockIdx.x * blockDim.x + tid;  // [0, B*HW)
  int b = t >> 15;
  int h = (t >> 8) & (Hc - 1);
  int w = t & (Wc - 1);
  float gx = -1.0f + (float)w * (2.0f / (Wc - 1));
  float gy = -1.0f + (float)h * (2.0f / (Hc - 1));
  unsigned m = 0;
#pragma unroll
  for (int j = 0; j < Nc; ++j) {
    int l = b * Nc + j;
    float t00 = wsf[l * 6 + 0], t01 = wsf[l * 6 + 1], t02 = wsf[l * 6 + 2];
    float t10 = wsf[l * 6 + 3], t11 = wsf[l * 6 + 4], t12 = wsf[l * 6 + 5];
    float cx = t00 * gx + t01 * gy + t02;
    float cy = t10 * gx + t11 * gy + t12;
    float ix = (cx + 1.0f) * 0.5f * (float)(Wc - 1);
    float iy = (cy + 1.0f) * 0.5f * (float)(Hc - 1);
    // vis: nearest sample of ones => in-bounds test of rounded coords
    int rx = (int)rintf(ix), ry = (int)rintf(iy);
    int vis = (rx >= 0 && rx < Wc && ry >= 0 && ry < Hc) ? 1 : 0;
    int comm = 1;  // agent 0 forced to 1
    if (j != 0) {
      float x0f = floorf(ix), y0f = floorf(iy);
      float fx = ix - x0f, fy = iy - y0f;
      int x0 = (int)x0f, y0 = (int)y0f;
      int x1 = x0 + 1, y1 = y0 + 1;
      bool vx0 = (x0 >= 0) && (x0 < Wc), vx1 = (x1 >= 0) && (x1 < Wc);
      bool vy0 = (y0 >= 0) && (y0 < Hc), vy1 = (y1 >= 0) && (y1 < Hc);
      int cx0 = min(max(x0, 0), Wc - 1), cx1 = min(max(x1, 0), Wc - 1);
      int cy0 = min(max(y0, 0), Hc - 1), cy1 = min(max(y1, 0), Hc - 1);
      int o00 = cy0 * Wc + cx0, o01 = cy0 * Wc + cx1;
      int o10 = cy1 * Wc + cx0, o11 = cy1 * Wc + cx1;
      float w00 = (vy0 && vx0) ? (1.0f - fy) * (1.0f - fx) : 0.0f;
      float w01 = (vy0 && vx1) ? (1.0f - fy) * fx : 0.0f;
      float w10 = (vy1 && vx0) ? fy * (1.0f - fx) : 0.0f;
      float w11 = (vy1 && vx1) ? fy * fx : 0.0f;
      float vmax = -INFINITY;
#pragma unroll
      for (int a = 0; a < Ac; ++a) {
        const float* p = psm + (size_t)(l * Ac + a) * HW;
        float v = p[o00] * w00 + p[o01] * w01 + p[o10] * w10 + p[o11] * w11;
        vmax = fmaxf(vmax, v);
      }
      comm = (vmax > LOGIT_THRESH) ? 1 : 0;
    }
    int owner = wsi[OWNER_OFF + l];
    int fin = comm & owner;
    m |= (unsigned)fin << j;
    unsigned long long bv = __ballot(vis != 0);
    unsigned long long bf = __ballot((fin & vis) != 0);
    if ((tid & 63) == 0) {
      atomicAdd(&cnt[j * 2 + 0], (int)__popcll(bv));
      atomicAdd(&cnt[j * 2 + 1], (int)__popcll(bf));
    }
  }
  mask[t] = (unsigned char)m;
  __syncthreads();
  if (tid < Nc * 2) partial[blockIdx.x * (Nc * 2) + tid] = cnt[tid];
}

// One thread per (b, c-octet, h, w): 8 channels share coords/weights/mask.
// out[b,c,h,w] = max_j final_j * bilinear(x[b*5+j, c]).
__global__ void __launch_bounds__(256) k_feat(const float* __restrict__ x,
                                              const float* __restrict__ wsf,
                                              const unsigned char* __restrict__ mask,
                                              float* __restrict__ out) {
  int t = blockIdx.x * blockDim.x + threadIdx.x;  // [0, B*(C/8)*HW)
  int w = t & (Wc - 1);
  int h = (t >> 8) & (Hc - 1);
  int c8 = (t >> 15) & (Cc / CPT - 1);
  int b = t >> 18;
  int pix = (b << 15) | (h << 8) | w;
  unsigned m = mask[pix];
  float gx = -1.0f + (float)w * (2.0f / (Wc - 1));
  float gy = -1.0f + (float)h * (2.0f / (Hc - 1));
  float best[CPT];
#pragma unroll
  for (int k = 0; k < CPT; ++k) best[k] = 0.0f;
#pragma unroll
  for (int j = 0; j < Nc; ++j) {
    if (m & (1u << j)) {
      int l = b * Nc + j;
      float t00 = wsf[l * 6 + 0], t01 = wsf[l * 6 + 1], t02 = wsf[l * 6 + 2];
      float t10 = wsf[l * 6 + 3], t11 = wsf[l * 6 + 4], t12 = wsf[l * 6 + 5];
      float cx = t00 * gx + t01 * gy + t02;
      float cy = t10 * gx + t11 * gy + t12;
      float ix = (cx + 1.0f) * 0.5f * (float)(Wc - 1);
      float iy = (cy + 1.0f) * 0.5f * (float)(Hc - 1);
      float x0f = floorf(ix), y0f = floorf(iy);
      float fx = ix - x0f, fy = iy - y0f;
      int x0 = (int)x0f, y0 = (int)y0f;
      int x1 = x0 + 1, y1 = y0 + 1;
      bool vx0 = (x0 >= 0) && (x0 < Wc), vx1 = (x1 >= 0) && (x1 < Wc);
      bool vy0 = (y0 >= 0) && (y0 < Hc), vy1 = (y1 >= 0) && (y1 < Hc);
      int cx0 = min(max(x0, 0), Wc - 1), cx1 = min(max(x1, 0), Wc - 1);
      int cy0 = min(max(y0, 0), Hc - 1), cy1 = min(max(y1, 0), Hc - 1);
      int o00 = cy0 * Wc + cx0, o01 = cy0 * Wc + cx1;
      int o10 = cy1 * Wc + cx0, o11 = cy1 * Wc + cx1;
      float w00 = (vy0 && vx0) ? (1.0f - fy) * (1.0f - fx) : 0.0f;
      float w01 = (vy0 && vx1) ? (1.0f - fy) * fx : 0.0f;
      float w10 = (vy1 && vx0) ? fy * (1.0f - fx) : 0.0f;
      float w11 = (vy1 && vx1) ? fy * fx : 0.0f;
      const float* p = x + ((size_t)(l * Cc + c8 * CPT)) * HW;
#pragma unroll
      for (int k = 0; k < CPT; ++k) {
        float val = p[o00] * w00 + p[o01] * w01 + p[o10] * w10 + p[o11] * w11;
        best[k] = fmaxf(best[k], val);
        p += HW;
      }
    }
  }
  size_t obase = ((size_t)(b * Cc + c8 * CPT)) * HW + (h << 8) + w;
#pragma unroll
  for (int k = 0; k < CPT; ++k) {
    __builtin_nontemporal_store(best[k], &out[obase + (size_t)k * HW]);
  }
}

// 1 block x 64 lanes: reduce 256 blocks x 10 partial counters, no atomics.
__global__ void k_rate(const int* __restrict__ partial, float* __restrict__ out) {
  int lane = threadIdx.x;  // 64
  float s = 0.0f;
  for (int l = 0; l < SUMN; ++l) {
    int b = l / Nc, j = l % Nc;
    int vis = 0, num = 0;
#pragma unroll
    for (int k = 0; k < MASK_BLOCKS / Bc / 64; ++k) {  // 128 blocks per b, 2 per lane
      int blk = b * (MASK_BLOCKS / Bc) + lane + 64 * k;
      vis += partial[blk * (Nc * 2) + j * 2 + 0];
      num += partial[blk * (Nc * 2) + j * 2 + 1];
    }
#pragma unroll
    for (int off = 32; off; off >>= 1) {
      vis += __shfl_down(vis, off);
      num += __shfl_down(num, off);
    }
    if (lane == 0) s += (float)num / fmaxf((float)vis, 1.0f);
  }
  if (lane == 0) out[(size_t)Bc * Cc * HW] = s / (float)SUMN;
}

}  // namespace

extern "C" void kernel_launch(void* const* d_in, const int* in_sizes, int n_in,
                              void* d_out, int out_size, void* d_ws, size_t ws_size,
                              hipStream_t stream) {
  const float* x = (const float*)d_in[0];
  const float* psm = (const float*)d_in[1];
  const float* nam = (const float*)d_in[2];
  // d_in[3] = record_len (compile-time constant Nc)
  float* out = (float*)d_out;
  float* wsf = (float*)d_ws;
  int* wsi = (int*)d_ws;
  int* partial = wsi + PART_OFF;
  unsigned char* mask = (unsigned char*)d_ws + MASK_BYTE_OFF;

  hipLaunchKernelGGL(k_setup, dim3(1), dim3(64), 0, stream, nam, wsf, wsi);
  hipLaunchKernelGGL(k_mask, dim3(MASK_BLOCKS), dim3(256), 0, stream, psm, wsf, wsi, partial,
                     mask);
  hipLaunchKernelGGL(k_feat, dim3((Bc * (Cc / CPT) * HW) / 256), dim3(256), 0, stream, x, wsf,
                     mask, out);
  hipLaunchKernelGGL(k_rate, dim3(1), dim3(1), 0, stream, partial, out);
}